// Round 4
// baseline (40.450 us; speedup 1.0000x reference)
//
#include <hip/hip_runtime.h>

// Zoom: out[b,c,t,f] = w*x[..., floor(f*k/n)] + (1-w)*x[..., floor(f*k/n)+1]
// Shape [8,16,256,1024] fp32; k, n runtime device scalars (k=2, n=3 here).
// R0 (67.8us): scalar global gathers -> TA/coalescer bound.
// R1 (68.5us): 4x row unroll, no change -> confirmed throughput (not latency) bound.
// R2 (39.8us): LDS staging + LDS gathers. Remaining gap vs ~28us floor =
//   exposed stage latency (vmcnt(0) drain per chunk) + VGPR round-trip staging.
// R3: global_load_lds width-16 DMA staging + 2-phase double buffer (T3 minimal:
//   issue stage(next) before compute(cur), one __syncthreads per iter) +
//   nontemporal stores (keep 134MB output stream from evicting L3-resident input).

typedef float f32x4 __attribute__((ext_vector_type(4)));

constexpr int F = 1024;          // last-dim size from reference shape
constexpr int VEC = 4;           // outputs per thread
constexpr int BLOCK = F / VEC;   // 256 threads = 4 waves: one block covers a row
constexpr int RU = 4;            // rows per chunk (2 x 16 KB LDS buffers)

__global__ __launch_bounds__(BLOCK) void zoom_kernel(
    const float* __restrict__ x,
    const int* __restrict__ kp,
    const int* __restrict__ np_,
    float* __restrict__ out,
    int nrows) {
  __shared__ float lds[2][RU][F];

  const int k = kp[0];
  const int n = np_[0];

  const int f0 = threadIdx.x * VEC;
  const int wv = threadIdx.x >> 6;   // wave id 0..3
  const int ln = threadIdx.x & 63;   // lane id

  // Loop-invariant interpolation coefficients for this thread's 4 columns.
  int  idx0[VEC], idx1[VEC];
  float w0[VEC], w1[VEC];
#pragma unroll
  for (int j = 0; j < VEC; ++j) {
    const int f   = f0 + j;
    const int pos = f * k;          // integer numerator of f*k/n
    const int id  = pos / n;        // floor(f*k/n)
    const int rem = pos - id * n;
    const float w = 1.0f - (float)rem / (float)n;  // matches reference op order
    const bool v0 = id < F;
    const bool v1 = (id + 1) < F;
    w0[j]   = v0 ? w : 0.0f;
    w1[j]   = v1 ? (1.0f - w) : 0.0f;
    idx0[j] = v0 ? id : 0;                      // clamped; weight already zeroed
    idx1[j] = v1 ? (id + 1) : (F - 1);
  }

  // Highest source word referenced: floor((F-1)*k/n)+1 -> stage in 256-word segs.
  int nwords = ((F - 1) * k) / n + 2;
  if (nwords > F) nwords = F;
  const int segs = (nwords + 255) >> 8;      // 1..4 segments of 256 words
  const int nstage = RU * segs;              // wave-level DMA instrs per chunk

  const int nchunks = (nrows + RU - 1) / RU;

  // Stage chunk into LDS buffer buf via global_load_lds (wave-uniform LDS base
  // + lane*16B = linear segment; global source per-lane). No VGPR round-trip.
  auto stage = [&](int chunk, int buf) {
    const size_t row0 = (size_t)chunk * RU;
    for (int s = wv; s < nstage; s += 4) {
      const int r   = s / segs;
      const int seg = s - r * segs;
      size_t row = row0 + (size_t)r;
      if (row >= (size_t)nrows) row = (size_t)nrows - 1;   // safe re-stage
      const float* gp = x + row * F + seg * 256 + ln * 4;  // 16B aligned
      float* lp = &lds[buf][r][seg * 256];                 // wave-uniform base
      __builtin_amdgcn_global_load_lds(
          (const __attribute__((address_space(1))) void*)gp,
          (__attribute__((address_space(3))) void*)lp, 16, 0, 0);
    }
  };

  const int c0 = blockIdx.x;
  int cur = 0;
  if (c0 < nchunks) stage(c0, 0);
  __syncthreads();   // vmcnt(0) drain: buf0 ready

  for (int c = c0; c < nchunks; c += gridDim.x) {
    const int cn = c + gridDim.x;
    if (cn < nchunks) stage(cn, cur ^ 1);   // in flight during compute(cur)

    const size_t row0 = (size_t)c * RU;
#pragma unroll
    for (int r = 0; r < RU; ++r) {
      if (row0 + (size_t)r >= (size_t)nrows) break;
      f32x4 v;
      v.x = w0[0] * lds[cur][r][idx0[0]] + w1[0] * lds[cur][r][idx1[0]];
      v.y = w0[1] * lds[cur][r][idx0[1]] + w1[1] * lds[cur][r][idx1[1]];
      v.z = w0[2] * lds[cur][r][idx0[2]] + w1[2] * lds[cur][r][idx1[2]];
      v.w = w0[3] * lds[cur][r][idx0[3]] + w1[3] * lds[cur][r][idx1[3]];
      __builtin_nontemporal_store(v, (f32x4*)(out + (row0 + (size_t)r) * F + f0));
    }

    __syncthreads();   // drains stage(cn) loads + orders LDS reuse; 1 barrier/iter
    cur ^= 1;
  }
}

extern "C" void kernel_launch(void* const* d_in, const int* in_sizes, int n_in,
                              void* d_out, int out_size, void* d_ws, size_t ws_size,
                              hipStream_t stream) {
  const float* x   = (const float*)d_in[0];
  const int*   kp  = (const int*)d_in[1];
  const int*   np_ = (const int*)d_in[2];
  float* out = (float*)d_out;

  const int total = in_sizes[0];        // 8*16*256*1024
  const int nrows = total / F;          // 32768

  const int nchunks = (nrows + RU - 1) / RU;   // 8192
  const int grid = (nchunks < 2048) ? nchunks : 2048;
  zoom_kernel<<<grid, BLOCK, 0, stream>>>(x, kp, np_, out, nrows);
}

// Round 5
// 39.425 us; speedup vs baseline: 1.0260x; 1.0260x over previous
//
#include <hip/hip_runtime.h>

// Zoom: out[b,c,t,f] = w*x[..., floor(f*k/n)] + (1-w)*x[..., floor(f*k/n)+1]
// Shape [8,16,256,1024] fp32; k, n runtime device scalars (k=2, n=3 here).
// R0 (67.8us): scalar global gathers -> TA/coalescer bound.
// R1 (68.5us): 4x row unroll, no change -> throughput (not latency) bound.
// R2 (39.8us): LDS staging + LDS gathers. 229MB moved = 5.7 TB/s = 91% of
//   m13 copy ceiling (6.29 TB/s combined).
// R3 (40.5us): DMA staging + dbuf NEUTRAL -> TLP already hides latency
//   (catalog T14-null regime). Binding constraint = total streamed bytes.
// R4: cut staged bytes to the compulsory 684 words/row (overlapped last
//   segment ending exactly at nwords; overlap re-read hits L2). Single
//   buffer, one chunk per block, grid=8192, ~8 blocks/CU for max TLP.
//   Floor: 88MB read + 131MB write = 219MB -> ~35us at copy ceiling.

typedef float f32x4 __attribute__((ext_vector_type(4)));

constexpr int F = 1024;          // last-dim size from reference shape
constexpr int VEC = 4;           // outputs per thread
constexpr int BLOCK = F / VEC;   // 256 threads = 4 waves: block covers a row
constexpr int RU = 4;            // rows per block (16 KB LDS)

__global__ __launch_bounds__(BLOCK) void zoom_kernel(
    const float* __restrict__ x,
    const int* __restrict__ kp,
    const int* __restrict__ np_,
    float* __restrict__ out,
    int nrows) {
  __shared__ float lds[RU][F];

  const int k = kp[0];
  const int n = np_[0];

  const int f0 = threadIdx.x * VEC;
  const int wv = threadIdx.x >> 6;   // wave id 0..3
  const int ln = threadIdx.x & 63;   // lane id

  // Loop-invariant interpolation coefficients for this thread's 4 columns.
  int  idx0[VEC], idx1[VEC];
  float w0[VEC], w1[VEC];
#pragma unroll
  for (int j = 0; j < VEC; ++j) {
    const int f   = f0 + j;
    const int pos = f * k;          // integer numerator of f*k/n
    const int id  = pos / n;        // floor(f*k/n)
    const int rem = pos - id * n;
    const float w = 1.0f - (float)rem / (float)n;  // matches reference op order
    const bool v0 = id < F;
    const bool v1 = (id + 1) < F;
    w0[j]   = v0 ? w : 0.0f;
    w1[j]   = v1 ? (1.0f - w) : 0.0f;
    idx0[j] = v0 ? id : 0;                      // clamped; weight already zeroed
    idx1[j] = v1 ? (id + 1) : (F - 1);
  }

  // Highest source word referenced: floor((F-1)*k/n)+1 -> nwords needed.
  int nwords = ((F - 1) * k) / n + 2;
  if (nwords > F) nwords = F;
  // Stage in 256-word (1 KB) wave segments. Last segment is shifted to end
  // exactly at nwords (start rounded UP to 4-word/16B alignment; overlap with
  // the previous segment re-reads L2-hot lines and rewrites identical data).
  const int segs = (nwords + 255) >> 8;          // 1..4
  int last_start = 0;
  if (nwords > 256) {
    last_start = (nwords - 256 + 3) & ~3;        // 16B-aligned, +256 >= nwords
  }
  const int nstage = RU * segs;

  const size_t row0 = (size_t)blockIdx.x * RU;

  // Stage: global_load_lds width-16 DMA (wave-uniform LDS base + lane*16B).
  for (int s = wv; s < nstage; s += 4) {
    const int r   = s / segs;
    const int seg = s - r * segs;
    const int start = (seg == segs - 1) ? last_start : seg * 256;
    size_t row = row0 + (size_t)r;
    if (row >= (size_t)nrows) row = (size_t)nrows - 1;   // safe re-stage
    const float* gp = x + row * F + start + ln * 4;      // 16B aligned
    float* lp = &lds[r][start];                          // wave-uniform base
    __builtin_amdgcn_global_load_lds(
        (const __attribute__((address_space(1))) void*)gp,
        (__attribute__((address_space(3))) void*)lp, 16, 0, 0);
  }
  __syncthreads();   // vmcnt(0) drain: all rows staged

  // Gather from LDS + nontemporal coalesced f32x4 store.
#pragma unroll
  for (int r = 0; r < RU; ++r) {
    if (row0 + (size_t)r >= (size_t)nrows) break;
    f32x4 v;
    v.x = w0[0] * lds[r][idx0[0]] + w1[0] * lds[r][idx1[0]];
    v.y = w0[1] * lds[r][idx0[1]] + w1[1] * lds[r][idx1[1]];
    v.z = w0[2] * lds[r][idx0[2]] + w1[2] * lds[r][idx1[2]];
    v.w = w0[3] * lds[r][idx0[3]] + w1[3] * lds[r][idx1[3]];
    __builtin_nontemporal_store(v, (f32x4*)(out + (row0 + (size_t)r) * F + f0));
  }
}

extern "C" void kernel_launch(void* const* d_in, const int* in_sizes, int n_in,
                              void* d_out, int out_size, void* d_ws, size_t ws_size,
                              hipStream_t stream) {
  const float* x   = (const float*)d_in[0];
  const int*   kp  = (const int*)d_in[1];
  const int*   np_ = (const int*)d_in[2];
  float* out = (float*)d_out;

  const int total = in_sizes[0];        // 8*16*256*1024
  const int nrows = total / F;          // 32768

  const int grid = (nrows + RU - 1) / RU;   // 8192 blocks, one chunk each
  zoom_kernel<<<grid, BLOCK, 0, stream>>>(x, kp, np_, out, nrows);
}